// Round 2
// baseline (1024.150 us; speedup 1.0000x reference)
//
#include <hip/hip_runtime.h>

#define NB 2048      // query positions
#define NOBS 2048    // observed positions
#define NP 15        // poly features
#define NG 21        // graph features
#define NE 64        // graph dict columns
#define ND 256       // opd dim
#define NK 36        // NP + NG
#define NDD (ND*ND)  // 65536
#define ROWS 256     // row tile per block in expansion

// ---------------------------------------------------------------------------
// Kernel 1: thread-per-query 1-NN + 36-entry coefficient build.
// 8 blocks x 256 threads; obs_pos (16 KB) + alpha matrices (6.2 KB) in LDS.
// No barriers after staging, no cross-thread reduction, no divergence.
// Ascending scan + strict '<' == argmin-first tie semantics.
// ---------------------------------------------------------------------------
__global__ __launch_bounds__(256) void knn_coeff_kernel(
    const float* __restrict__ positions,   // [NB][2]
    const float* __restrict__ obs_pos,     // [NOBS][2]
    const float* __restrict__ poly_dic,    // [NOBS][NP]
    const float* __restrict__ graph_dic,   // [NOBS][NE]
    const float* __restrict__ alpha_poly,  // [NP][NP]
    const float* __restrict__ alpha_graph, // [NE][NG]
    float* __restrict__ coeff)             // [NB][NK]
{
    __shared__ float2 sobs[NOBS];          // 16 KB
    __shared__ float  sap[NP*NP];          // 900 B
    __shared__ float  sag[NE*NG];          // 5376 B

    const int tid = threadIdx.x;
    const int b   = blockIdx.x * 256 + tid;

    const float2* obs2 = (const float2*)obs_pos;
    for (int i = tid; i < NOBS; i += 256)  sobs[i] = obs2[i];
    for (int i = tid; i < NP*NP; i += 256) sap[i]  = alpha_poly[i];
    for (int i = tid; i < NE*NG; i += 256) sag[i]  = alpha_graph[i];

    const float2 q = ((const float2*)positions)[b];  // coalesced
    __syncthreads();

    float bestd = 3.4e38f;
    int   besti = 0;
    #pragma unroll 8
    for (int i = 0; i < NOBS; ++i) {
        const float dx = q.x - sobs[i].x;
        const float dy = q.y - sobs[i].y;
        const float d2 = dx*dx + dy*dy;
        if (d2 < bestd) { bestd = d2; besti = i; }
    }

    float* crow = coeff + (size_t)b * NK;

    // poly: crow[0:15] = poly_dic[besti] @ alpha_poly
    float pv[NP];
    const float* prow = poly_dic + (size_t)besti * NP;
    #pragma unroll
    for (int qq = 0; qq < NP; ++qq) pv[qq] = prow[qq];
    for (int p = 0; p < NP; ++p) {
        float acc = 0.f;
        #pragma unroll
        for (int qq = 0; qq < NP; ++qq) acc += pv[qq] * sap[qq*NP + p];
        crow[p] = acc;
    }

    // graph: crow[15:36] = graph_dic[besti] @ alpha_graph
    float gv[NE];
    const float4* grow = (const float4*)(graph_dic + (size_t)besti * NE); // 256B-aligned rows
    #pragma unroll
    for (int u = 0; u < NE/4; ++u) {
        const float4 t = grow[u];
        gv[4*u+0] = t.x; gv[4*u+1] = t.y; gv[4*u+2] = t.z; gv[4*u+3] = t.w;
    }
    for (int g = 0; g < NG; ++g) {
        float acc = 0.f;
        #pragma unroll
        for (int e = 0; e < NE; ++e) acc += gv[e] * sag[e*NG + g];
        crow[NP + g] = acc;
    }
}

// ---------------------------------------------------------------------------
// Kernel 2: out[b][j] = sum_k coeff[b][k] * S_all[k][j]
// Each thread owns TWO adjacent columns (float2 s[36] in VGPRs) -> coeff
// load:fmac ratio 1:2, coeff fetched as 9x float4 per row (uniform-address
// broadcast, L1-resident). grid (128, 8) = 1024 blocks = 4/CU; launch_bounds
// (256,4) caps VGPRs at 128 for 4 waves/SIMD.
// ---------------------------------------------------------------------------
__global__ __launch_bounds__(256, 4) void expand_kernel(
    const float* __restrict__ coeff,    // [NB][NK]
    const float* __restrict__ S_poly,   // [NP][NDD]
    const float* __restrict__ S_graph,  // [NG][NDD]
    float* __restrict__ out)            // [NB][NDD]
{
    const int tid = threadIdx.x;
    const int j0  = (blockIdx.x * 256 + tid) * 2;
    const int b0  = blockIdx.y * ROWS;

    float2 s[NK];
    #pragma unroll
    for (int k = 0; k < NP; ++k)
        s[k] = *(const float2*)(S_poly + (size_t)k * NDD + j0);
    #pragma unroll
    for (int k = 0; k < NG; ++k)
        s[NP + k] = *(const float2*)(S_graph + (size_t)k * NDD + j0);

    for (int bb = 0; bb < ROWS; ++bb) {
        const float4* c4 = (const float4*)(coeff + (size_t)(b0 + bb) * NK); // 144B rows, 16B-aligned
        float4 c[9];
        #pragma unroll
        for (int u = 0; u < 9; ++u) c[u] = c4[u];

        float a0 = 0.f, a1 = 0.f;
        #pragma unroll
        for (int u = 0; u < 9; ++u) {
            a0 += c[u].x * s[4*u+0].x;  a1 += c[u].x * s[4*u+0].y;
            a0 += c[u].y * s[4*u+1].x;  a1 += c[u].y * s[4*u+1].y;
            a0 += c[u].z * s[4*u+2].x;  a1 += c[u].z * s[4*u+2].y;
            a0 += c[u].w * s[4*u+3].x;  a1 += c[u].w * s[4*u+3].y;
        }

        float2 r; r.x = a0; r.y = a1;
        *(float2*)(out + (size_t)(b0 + bb) * NDD + j0) = r;
    }
}

extern "C" void kernel_launch(void* const* d_in, const int* in_sizes, int n_in,
                              void* d_out, int out_size, void* d_ws, size_t ws_size,
                              hipStream_t stream) {
    const float* positions   = (const float*)d_in[0];
    const float* obs_pos     = (const float*)d_in[1];
    const float* poly_dic    = (const float*)d_in[2];
    const float* graph_dic   = (const float*)d_in[3];
    const float* alpha_poly  = (const float*)d_in[4];
    const float* alpha_graph = (const float*)d_in[5];
    const float* S_poly      = (const float*)d_in[6];
    const float* S_graph     = (const float*)d_in[7];
    float* out = (float*)d_out;

    float* coeff = (float*)d_ws;   // NB*NK floats = 288 KB

    knn_coeff_kernel<<<NB/256, 256, 0, stream>>>(
        positions, obs_pos, poly_dic, graph_dic, alpha_poly, alpha_graph, coeff);

    dim3 grid2(NDD/512, NB/ROWS);
    expand_kernel<<<grid2, 256, 0, stream>>>(coeff, S_poly, S_graph, out);
}